// Round 2
// baseline (374.008 us; speedup 1.0000x reference)
//
#include <hip/hip_runtime.h>
#include <hip/hip_bf16.h>

#define DEV __device__ __forceinline__

// all-thread block reduction (256 threads), returns totals in s, s2 for every thread
DEV void blockReduce2(float& s, float& s2, float* ps, float* ps2, int tid){
  #pragma unroll
  for (int o = 32; o > 0; o >>= 1){ s += __shfl_xor(s, o); s2 += __shfl_xor(s2, o); }
  int w = tid >> 6;
  if ((tid & 63) == 0){ ps[w] = s; ps2[w] = s2; }
  __syncthreads();
  s  = ps[0] + ps[1] + ps[2] + ps[3];
  s2 = ps2[0] + ps2[1] + ps2[2] + ps2[3];
}

// K0: LN1 over C=256 per (b,n) row. grid=6272, block=256
__global__ __launch_bounds__(256) void kLN1(const float* __restrict__ x, const float* __restrict__ g,
                                            const float* __restrict__ be, float* __restrict__ xn){
  __shared__ float ps[4], ps2[4];
  int bn = blockIdx.x, t = threadIdx.x;
  float v = x[(size_t)bn*256 + t];
  float s = v, s2 = v*v;
  blockReduce2(s, s2, ps, ps2, t);
  float m  = s * (1.f/256.f);
  float var = s2 * (1.f/256.f) - m*m;
  float rs = rsqrtf(var + 1e-3f);
  xn[(size_t)bn*256 + t] = (v - m)*rs*g[t] + be[t];
}

// K1: per-n GEMM [32x256]@[256x1536] + b1 + exact gelu -> y. grid=196*6, block=256
__global__ __launch_bounds__(256) void kExpand(const float* __restrict__ xn, const float* __restrict__ W1,
                                               const float* __restrict__ b1, float* __restrict__ y){
  __shared__ float As[32][260];
  int bid = blockIdx.x;
  int n = bid / 6, et = bid % 6;
  int tid = threadIdx.x;
  #pragma unroll
  for (int b = 0; b < 32; ++b) As[b][tid] = xn[(size_t)(b*196 + n)*256 + tid];
  __syncthreads();
  int e0 = et*256 + tid;
  const float* wp = W1 + (size_t)n*393216 + e0;   // 256*1536
  float acc[32];
  #pragma unroll
  for (int b = 0; b < 32; ++b) acc[b] = 0.f;
  for (int c = 0; c < 256; c += 4){
    float w0 = wp[(size_t)(c+0)*1536];
    float w1 = wp[(size_t)(c+1)*1536];
    float w2 = wp[(size_t)(c+2)*1536];
    float w3 = wp[(size_t)(c+3)*1536];
    #pragma unroll
    for (int b = 0; b < 32; ++b){
      float4 a = *(const float4*)&As[b][c];
      acc[b] = fmaf(a.w, w3, fmaf(a.z, w2, fmaf(a.y, w1, fmaf(a.x, w0, acc[b]))));
    }
  }
  float bb = b1[(size_t)n*1536 + e0];
  #pragma unroll
  for (int b = 0; b < 32; ++b){
    float v = acc[b] + bb;
    v = 0.5f*v*(1.f + erff(v*0.70710678118654752f));   // exact gelu
    y[(size_t)(b*196 + n)*1536 + e0] = v;
  }
}

// K2: LN2 stats over H=768 (u half of y) per (b,n). grid=6272, block=256
__global__ __launch_bounds__(256) void kStats2(const float* __restrict__ y, float2* __restrict__ stats){
  __shared__ float ps[4], ps2[4];
  int bn = blockIdx.x, t = threadIdx.x;
  const float* r = y + (size_t)bn*1536;
  float a0 = r[t], a1 = r[t+256], a2 = r[t+512];
  float s = a0+a1+a2, s2 = a0*a0 + a1*a1 + a2*a2;
  blockReduce2(s, s2, ps, ps2, t);
  float m   = s * (1.f/768.f);
  float var = s2 * (1.f/768.f) - m*m;
  if (t == 0) stats[bn] = make_float2(m, rsqrtf(var + 1e-3f));
}

// K3/K5: 64x64 tiled fp32 transpose [R rows x Cc cols] -> [Cc x R].
// If stats!=null, applies LN2 affine to columns c<768 (u half) while loading.
__global__ __launch_bounds__(256) void kTrans(const float* __restrict__ in, float* __restrict__ out,
                                              int R, int Cc, const float2* __restrict__ stats,
                                              const float* __restrict__ g2, const float* __restrict__ be2){
  __shared__ float T[64][65];
  int ntc = Cc >> 6;
  int rt = blockIdx.x / ntc, ct = blockIdx.x % ntc;
  int r0 = rt << 6, c0 = ct << 6;
  int l = threadIdx.x & 63, q = threadIdx.x >> 6;
  bool doLN = (stats != nullptr) && (c0 < 768);
  float gv = 1.f, bv = 0.f;
  if (doLN){ gv = g2[c0 + l]; bv = be2[c0 + l]; }
  #pragma unroll
  for (int i = 0; i < 16; ++i){
    int r = (i << 2) + q;
    float val = in[(size_t)(r0 + r)*Cc + c0 + l];
    if (doLN){ float2 st = stats[r0 + r]; val = (val - st.x)*st.y*gv + bv; }
    T[l][r] = val;
  }
  __syncthreads();
  #pragma unroll
  for (int i = 0; i < 16; ++i){
    int c = (i << 2) + q;
    out[(size_t)(c0 + c)*R + r0 + l] = T[c][l];
  }
}

// K4: per-d GEMM [32x196]@[196x196] + b2^T, times v -> zT. grid=768, block=256
__global__ __launch_bounds__(256) void kSGU(const float* __restrict__ yT, const float* __restrict__ W2,
                                            const float* __restrict__ b2, float* __restrict__ zT){
  __shared__ float A2[6272];
  int d = blockIdx.x, tid = threadIdx.x;
  const float* up = yT + (size_t)d*6272;
  for (int i = 0; i < 25; ++i){ int idx = i*256 + tid; if (idx < 6272) A2[idx] = up[idx]; }
  __syncthreads();
  if (tid < 196){
    const float* wp = W2 + (size_t)d*38416 + tid;   // 196*196
    float acc[32];
    #pragma unroll
    for (int b = 0; b < 32; ++b) acc[b] = 0.f;
    for (int m = 0; m < 196; m += 4){
      float w0 = wp[(m+0)*196];
      float w1 = wp[(m+1)*196];
      float w2v = wp[(m+2)*196];
      float w3 = wp[(m+3)*196];
      #pragma unroll
      for (int b = 0; b < 32; ++b){
        float4 a = *(const float4*)&A2[b*196 + m];
        acc[b] = fmaf(a.w, w3, fmaf(a.z, w2v, fmaf(a.y, w1, fmaf(a.x, w0, acc[b]))));
      }
    }
    float b2v = b2[(size_t)d*196 + tid];
    const float* vp = yT + (size_t)4816896 + (size_t)d*6272 + tid;   // v half: rows 768..1535
    float* zp = zT + (size_t)d*6272 + tid;
    #pragma unroll
    for (int b = 0; b < 32; ++b){
      float u2 = acc[b] + b2v;
      float vv = vp[b*196];
      zp[b*196] = u2*vv;
    }
  }
}

// K6: per-(n, d-quarter) GEMM [32x192]@[192x256] -> fp32 partials. grid=196*4, block=256
__global__ __launch_bounds__(256) void kOut(const float* __restrict__ z, const float* __restrict__ W3,
                                            float* __restrict__ part){
  __shared__ float A3[32*192];
  int bid = blockIdx.x;
  int n = bid >> 2, h = bid & 3;
  int tid = threadIdx.x;
  const float* zp = z + (size_t)n*768 + h*192;
  if (tid < 192){
    #pragma unroll
    for (int b = 0; b < 32; ++b) A3[b*192 + tid] = zp[(size_t)b*150528 + tid];
  }
  __syncthreads();
  const float* wp = W3 + ((size_t)n*768 + h*192)*256 + tid;
  float acc[32];
  #pragma unroll
  for (int b = 0; b < 32; ++b) acc[b] = 0.f;
  for (int j = 0; j < 192; j += 4){
    float w0 = wp[(size_t)(j+0)*256];
    float w1 = wp[(size_t)(j+1)*256];
    float w2 = wp[(size_t)(j+2)*256];
    float w3 = wp[(size_t)(j+3)*256];
    #pragma unroll
    for (int b = 0; b < 32; ++b){
      float4 a = *(const float4*)&A3[b*192 + j];
      acc[b] = fmaf(a.w, w3, fmaf(a.z, w2, fmaf(a.y, w1, fmaf(a.x, w0, acc[b]))));
    }
  }
  float* pp = part + (size_t)h*1605632 + (size_t)n*256 + tid;
  #pragma unroll
  for (int b = 0; b < 32; ++b) pp[(size_t)b*50176] = acc[b];
}

// K7: out = sum of 4 partials + b3 + x. grid=3136, block=256 (2 elems/thread)
__global__ __launch_bounds__(256) void kFinal(const float* __restrict__ part, const float* __restrict__ x,
                                              const float* __restrict__ b3, float* __restrict__ out){
  int i2 = blockIdx.x*256 + threadIdx.x;     // pair index < 802816
  size_t idx = (size_t)i2 * 2;
  const float2* p = (const float2*)part;
  float2 s0 = p[i2];
  float2 s1 = p[i2 + 802816];
  float2 s2 = p[i2 + 2*802816];
  float2 s3 = p[i2 + 3*802816];
  float lo = s0.x + s1.x + s2.x + s3.x;
  float hi = s0.y + s1.y + s2.y + s3.y;
  float2 xv = ((const float2*)x)[i2];
  unsigned int r = (unsigned int)(idx % 50176);   // b3 repeats per batch; r is even
  float2 bv = *(const float2*)(b3 + r);
  lo += xv.x + bv.x;
  hi += xv.y + bv.y;
  ((float2*)out)[i2] = make_float2(lo, hi);
}

extern "C" void kernel_launch(void* const* d_in, const int* in_sizes, int n_in,
                              void* d_out, int out_size, void* d_ws, size_t ws_size,
                              hipStream_t stream){
  const float* x   = (const float*)d_in[0];
  const float* g1  = (const float*)d_in[1];
  const float* be1 = (const float*)d_in[2];
  const float* W1  = (const float*)d_in[3];
  const float* b1  = (const float*)d_in[4];
  const float* g2  = (const float*)d_in[5];
  const float* be2 = (const float*)d_in[6];
  const float* W2  = (const float*)d_in[7];
  const float* b2  = (const float*)d_in[8];
  const float* W3  = (const float*)d_in[9];
  const float* b3  = (const float*)d_in[10];
  float* out = (float*)d_out;

  char* ws = (char*)d_ws;
  size_t off = 0;
  auto alloc = [&](size_t bytes) -> void* {
    void* p = ws + off;
    off += (bytes + 255) & ~(size_t)255;
    return p;
  };
  // Region A: xn (dead after kExpand)
  float*  xn    = (float*) alloc((size_t)1605632*4);
  // Region B: y [6272][1536] (dead after kTrans1); later reused for zT + z
  float*  y     = (float*) alloc((size_t)9633792*4);
  // Region C: LN2 stats
  float2* stats = (float2*)alloc((size_t)6272*8);
  // Region D: yT [1536][6272] (dead after kSGU); later reused for part
  float*  yT    = (float*) alloc((size_t)9633792*4);
  if (off > ws_size) return;  // workspace too small; fail loudly in validation

  float* zT   = y;                 // [768][6272], aliases y (y dead by kSGU)
  float* z    = y + 4816896;       // [6272][768]
  float* part = yT;                // 4*1605632 floats, aliases yT (dead by kOut)

  kLN1   <<<6272, 256, 0, stream>>>(x, g1, be1, xn);
  kExpand<<<1176, 256, 0, stream>>>(xn, W1, b1, y);
  kStats2<<<6272, 256, 0, stream>>>(y, stats);
  kTrans <<<2352, 256, 0, stream>>>(y, yT, 6272, 1536, stats, g2, be2);
  kSGU   <<<768,  256, 0, stream>>>(yT, W2, b2, zT);
  kTrans <<<1176, 256, 0, stream>>>(zT, z, 768, 6272, nullptr, nullptr, nullptr);
  kOut   <<<784,  256, 0, stream>>>(z, W3, part);
  kFinal <<<3136, 256, 0, stream>>>(part, x, b3, out);
}

// Round 3
// 280.302 us; speedup vs baseline: 1.3343x; 1.3343x over previous
//
#include <hip/hip_runtime.h>
#include <hip/hip_bf16.h>

#define DEV __device__ __forceinline__

typedef unsigned short u16;
typedef unsigned int   u32;
typedef __attribute__((ext_vector_type(8))) short bf16x8;
typedef __attribute__((ext_vector_type(4))) float f32x4;

DEV u16 f2bf(float f){
  u32 u = __float_as_uint(f);
  u32 r = (u + 0x7FFFu + ((u >> 16) & 1u)) >> 16;
  return (u16)r;
}
DEV u32 pack2(float lo, float hi){ return (u32)f2bf(lo) | ((u32)f2bf(hi) << 16); }

// all-thread block reduction (256 threads), returns totals in s, s2 for every thread
DEV void blockReduce2(float& s, float& s2, float* ps, float* ps2, int tid){
  #pragma unroll
  for (int o = 32; o > 0; o >>= 1){ s += __shfl_xor(s, o); s2 += __shfl_xor(s2, o); }
  int w = tid >> 6;
  if ((tid & 63) == 0){ ps[w] = s; ps2[w] = s2; }
  __syncthreads();
  s  = ps[0] + ps[1] + ps[2] + ps[3];
  s2 = ps2[0] + ps2[1] + ps2[2] + ps2[3];
}

// K0: LN1 over C=256 per (b,n) row. grid=6272, block=256
__global__ __launch_bounds__(256) void kLN1(const float* __restrict__ x, const float* __restrict__ g,
                                            const float* __restrict__ be, float* __restrict__ xn){
  __shared__ float ps[4], ps2[4];
  int bn = blockIdx.x, t = threadIdx.x;
  float v = x[(size_t)bn*256 + t];
  float s = v, s2 = v*v;
  blockReduce2(s, s2, ps, ps2, t);
  float m  = s * (1.f/256.f);
  float var = s2 * (1.f/256.f) - m*m;
  float rs = rsqrtf(var + 1e-3f);
  xn[(size_t)bn*256 + t] = (v - m)*rs*g[t] + be[t];
}

// K1 (MFMA): per-n GEMM [32x256]@[256x1536] + b1 + exact gelu -> y fp32.
// grid = 196*6 (n, 256-wide e-chunk), block = 256 (4 waves, each 64 e-cols).
// A: LDS bf16 [32][256], XOR-swizzled 16B groups. B: streamed fp32->bf16,
// LDS [256 e][40 bf16] pitch 80 B (k-major within row), reg-staged per k-step.
__global__ __launch_bounds__(256) void kExpand(const float* __restrict__ xn, const float* __restrict__ W1,
                                               const float* __restrict__ b1, float* __restrict__ y){
  __shared__ unsigned char sm[36864];      // A: [0,16384)  B: [16384, 36864)
  unsigned char* smA = sm;
  unsigned char* smB = sm + 16384;
  int bid = blockIdx.x;
  int n = bid / 6, et = bid % 6;
  int tid = threadIdx.x;
  int e0 = et*256;

  // ---- stage A: xn[b][n][0..255] -> bf16 LDS, swizzled ----
  {
    int r = tid >> 3;                                  // batch row 0..31
    const float* src = xn + ((size_t)(r*196 + n))*256;
    #pragma unroll
    for (int i = 0; i < 4; ++i){
      int g = (tid & 7) + 8*i;                         // 16B-group 0..31
      int k0 = g*8;
      float4 a0 = *(const float4*)(src + k0);
      float4 a1 = *(const float4*)(src + k0 + 4);
      uint4 wv;
      wv.x = pack2(a0.x, a0.y); wv.y = pack2(a0.z, a0.w);
      wv.z = pack2(a1.x, a1.y); wv.w = pack2(a1.z, a1.w);
      int byte = r*512 + ((g*16) ^ ((r & 7) << 4));
      *(uint4*)(smA + byte) = wv;
    }
  }

  const float* wbase = W1 + (size_t)n*393216 + e0 + tid;   // lane owns column e0+tid
  float stg[4][8];
  // prologue: load k-step 0
  #pragma unroll
  for (int p = 0; p < 4; ++p)
    #pragma unroll
    for (int j = 0; j < 8; ++j)
      stg[p][j] = wbase[(size_t)(p*8 + j)*1536];
  __syncthreads();                                   // A visible; B not yet read
  #pragma unroll
  for (int p = 0; p < 4; ++p){
    uint4 wv;
    wv.x = pack2(stg[p][0], stg[p][1]); wv.y = pack2(stg[p][2], stg[p][3]);
    wv.z = pack2(stg[p][4], stg[p][5]); wv.w = pack2(stg[p][6], stg[p][7]);
    *(uint4*)(smB + tid*80 + p*16) = wv;
  }
  __syncthreads();

  int w = tid >> 6, l = tid & 63;
  f32x4 acc[2][4];
  #pragma unroll
  for (int mt = 0; mt < 2; ++mt)
    #pragma unroll
    for (int nt = 0; nt < 4; ++nt)
      acc[mt][nt] = (f32x4){0.f, 0.f, 0.f, 0.f};

  for (int ks = 0; ks < 8; ++ks){
    // issue next k-step's global loads early (hide HBM under MFMA)
    if (ks < 7){
      #pragma unroll
      for (int p = 0; p < 4; ++p)
        #pragma unroll
        for (int j = 0; j < 8; ++j)
          stg[p][j] = wbase[(size_t)((ks+1)*32 + p*8 + j)*1536];
    }
    // fragments + MFMA for current step
    bf16x8 afr[2], bfr[4];
    #pragma unroll
    for (int mt = 0; mt < 2; ++mt){
      int row = mt*16 + (l & 15);
      int kb  = ks*64 + ((l >> 4) << 4);
      afr[mt] = *(const bf16x8*)(smA + row*512 + (kb ^ ((row & 7) << 4)));
    }
    #pragma unroll
    for (int nt = 0; nt < 4; ++nt){
      int e = w*64 + nt*16 + (l & 15);
      bfr[nt] = *(const bf16x8*)(smB + e*80 + ((l >> 4) << 4));
    }
    #pragma unroll
    for (int mt = 0; mt < 2; ++mt)
      #pragma unroll
      for (int nt = 0; nt < 4; ++nt)
        acc[mt][nt] = __builtin_amdgcn_mfma_f32_16x16x32_bf16(afr[mt], bfr[nt], acc[mt][nt], 0, 0, 0);
    if (ks < 7){
      __syncthreads();                 // all frag reads done before overwrite
      #pragma unroll
      for (int p = 0; p < 4; ++p){
        uint4 wv;
        wv.x = pack2(stg[p][0], stg[p][1]); wv.y = pack2(stg[p][2], stg[p][3]);
        wv.z = pack2(stg[p][4], stg[p][5]); wv.w = pack2(stg[p][6], stg[p][7]);
        *(uint4*)(smB + tid*80 + p*16) = wv;
      }
      __syncthreads();                 // new B visible
    }
  }

  // ---- epilogue: bias + exact gelu + store fp32 ----
  #pragma unroll
  for (int nt = 0; nt < 4; ++nt){
    int e = e0 + w*64 + nt*16 + (l & 15);
    float bb = b1[(size_t)n*1536 + e];
    #pragma unroll
    for (int mt = 0; mt < 2; ++mt){
      #pragma unroll
      for (int r = 0; r < 4; ++r){
        int b = mt*16 + ((l >> 4) << 2) + r;           // C/D: row=(lane>>4)*4+reg
        float v = acc[mt][nt][r] + bb;
        v = 0.5f*v*(1.f + erff(v*0.70710678118654752f));
        y[((size_t)(b*196 + n))*1536 + e] = v;
      }
    }
  }
}

// K2: LN2 stats over H=768 (u half of y) per (b,n). grid=6272, block=256
__global__ __launch_bounds__(256) void kStats2(const float* __restrict__ y, float2* __restrict__ stats){
  __shared__ float ps[4], ps2[4];
  int bn = blockIdx.x, t = threadIdx.x;
  const float* r = y + (size_t)bn*1536;
  float a0 = r[t], a1 = r[t+256], a2 = r[t+512];
  float s = a0+a1+a2, s2 = a0*a0 + a1*a1 + a2*a2;
  blockReduce2(s, s2, ps, ps2, t);
  float m   = s * (1.f/768.f);
  float var = s2 * (1.f/768.f) - m*m;
  if (t == 0) stats[bn] = make_float2(m, rsqrtf(var + 1e-3f));
}

// K3/K5: 64x64 tiled fp32 transpose [R rows x Cc cols] -> [Cc x R].
// If stats!=null, applies LN2 affine to columns c<768 (u half) while loading.
__global__ __launch_bounds__(256) void kTrans(const float* __restrict__ in, float* __restrict__ out,
                                              int R, int Cc, const float2* __restrict__ stats,
                                              const float* __restrict__ g2, const float* __restrict__ be2){
  __shared__ float T[64][65];
  int ntc = Cc >> 6;
  int rt = blockIdx.x / ntc, ct = blockIdx.x % ntc;
  int r0 = rt << 6, c0 = ct << 6;
  int l = threadIdx.x & 63, q = threadIdx.x >> 6;
  bool doLN = (stats != nullptr) && (c0 < 768);
  float gv = 1.f, bv = 0.f;
  if (doLN){ gv = g2[c0 + l]; bv = be2[c0 + l]; }
  #pragma unroll
  for (int i = 0; i < 16; ++i){
    int r = (i << 2) + q;
    float val = in[(size_t)(r0 + r)*Cc + c0 + l];
    if (doLN){ float2 st = stats[r0 + r]; val = (val - st.x)*st.y*gv + bv; }
    T[l][r] = val;
  }
  __syncthreads();
  #pragma unroll
  for (int i = 0; i < 16; ++i){
    int c = (i << 2) + q;
    out[(size_t)(c0 + c)*R + r0 + l] = T[c][l];
  }
}

// K4: per-d GEMM [32x196]@[196x196] + b2^T, times v -> zT. grid=768, block=256
__global__ __launch_bounds__(256) void kSGU(const float* __restrict__ yT, const float* __restrict__ W2,
                                            const float* __restrict__ b2, float* __restrict__ zT){
  __shared__ float A2[6272];
  int d = blockIdx.x, tid = threadIdx.x;
  const float* up = yT + (size_t)d*6272;
  for (int i = 0; i < 25; ++i){ int idx = i*256 + tid; if (idx < 6272) A2[idx] = up[idx]; }
  __syncthreads();
  if (tid < 196){
    const float* wp = W2 + (size_t)d*38416 + tid;   // 196*196
    float acc[32];
    #pragma unroll
    for (int b = 0; b < 32; ++b) acc[b] = 0.f;
    for (int m = 0; m < 196; m += 4){
      float w0 = wp[(m+0)*196];
      float w1 = wp[(m+1)*196];
      float w2v = wp[(m+2)*196];
      float w3 = wp[(m+3)*196];
      #pragma unroll
      for (int b = 0; b < 32; ++b){
        float4 a = *(const float4*)&A2[b*196 + m];
        acc[b] = fmaf(a.w, w3, fmaf(a.z, w2v, fmaf(a.y, w1, fmaf(a.x, w0, acc[b]))));
      }
    }
    float b2v = b2[(size_t)d*196 + tid];
    const float* vp = yT + (size_t)4816896 + (size_t)d*6272 + tid;   // v half: rows 768..1535
    float* zp = zT + (size_t)d*6272 + tid;
    #pragma unroll
    for (int b = 0; b < 32; ++b){
      float u2 = acc[b] + b2v;
      float vv = vp[b*196];
      zp[b*196] = u2*vv;
    }
  }
}

// K6: per-(n, d-quarter) GEMM [32x192]@[192x256] -> fp32 partials. grid=196*4, block=256
__global__ __launch_bounds__(256) void kOut(const float* __restrict__ z, const float* __restrict__ W3,
                                            float* __restrict__ part){
  __shared__ float A3[32*192];
  int bid = blockIdx.x;
  int n = bid >> 2, h = bid & 3;
  int tid = threadIdx.x;
  const float* zp = z + (size_t)n*768 + h*192;
  if (tid < 192){
    #pragma unroll
    for (int b = 0; b < 32; ++b) A3[b*192 + tid] = zp[(size_t)b*150528 + tid];
  }
  __syncthreads();
  const float* wp = W3 + ((size_t)n*768 + h*192)*256 + tid;
  float acc[32];
  #pragma unroll
  for (int b = 0; b < 32; ++b) acc[b] = 0.f;
  for (int j = 0; j < 192; j += 4){
    float w0 = wp[(size_t)(j+0)*256];
    float w1 = wp[(size_t)(j+1)*256];
    float w2 = wp[(size_t)(j+2)*256];
    float w3 = wp[(size_t)(j+3)*256];
    #pragma unroll
    for (int b = 0; b < 32; ++b){
      float4 a = *(const float4*)&A3[b*192 + j];
      acc[b] = fmaf(a.w, w3, fmaf(a.z, w2, fmaf(a.y, w1, fmaf(a.x, w0, acc[b]))));
    }
  }
  float* pp = part + (size_t)h*1605632 + (size_t)n*256 + tid;
  #pragma unroll
  for (int b = 0; b < 32; ++b) pp[(size_t)b*50176] = acc[b];
}

// K7: out = sum of 4 partials + b3 + x. grid=3136, block=256 (2 elems/thread)
__global__ __launch_bounds__(256) void kFinal(const float* __restrict__ part, const float* __restrict__ x,
                                              const float* __restrict__ b3, float* __restrict__ out){
  int i2 = blockIdx.x*256 + threadIdx.x;     // pair index < 802816
  size_t idx = (size_t)i2 * 2;
  const float2* p = (const float2*)part;
  float2 s0 = p[i2];
  float2 s1 = p[i2 + 802816];
  float2 s2 = p[i2 + 2*802816];
  float2 s3 = p[i2 + 3*802816];
  float lo = s0.x + s1.x + s2.x + s3.x;
  float hi = s0.y + s1.y + s2.y + s3.y;
  float2 xv = ((const float2*)x)[i2];
  unsigned int r = (unsigned int)(idx % 50176);   // b3 repeats per batch; r is even
  float2 bv = *(const float2*)(b3 + r);
  lo += xv.x + bv.x;
  hi += xv.y + bv.y;
  ((float2*)out)[i2] = make_float2(lo, hi);
}

extern "C" void kernel_launch(void* const* d_in, const int* in_sizes, int n_in,
                              void* d_out, int out_size, void* d_ws, size_t ws_size,
                              hipStream_t stream){
  const float* x   = (const float*)d_in[0];
  const float* g1  = (const float*)d_in[1];
  const float* be1 = (const float*)d_in[2];
  const float* W1  = (const float*)d_in[3];
  const float* b1  = (const float*)d_in[4];
  const float* g2  = (const float*)d_in[5];
  const float* be2 = (const float*)d_in[6];
  const float* W2  = (const float*)d_in[7];
  const float* b2  = (const float*)d_in[8];
  const float* W3  = (const float*)d_in[9];
  const float* b3  = (const float*)d_in[10];
  float* out = (float*)d_out;

  char* ws = (char*)d_ws;
  size_t off = 0;
  auto alloc = [&](size_t bytes) -> void* {
    void* p = ws + off;
    off += (bytes + 255) & ~(size_t)255;
    return p;
  };
  // Region A: xn (dead after kExpand)
  float*  xn    = (float*) alloc((size_t)1605632*4);
  // Region B: y [6272][1536] (dead after kTrans1); later reused for zT + z
  float*  y     = (float*) alloc((size_t)9633792*4);
  // Region C: LN2 stats
  float2* stats = (float2*)alloc((size_t)6272*8);
  // Region D: yT [1536][6272] (dead after kSGU); later reused for part
  float*  yT    = (float*) alloc((size_t)9633792*4);
  if (off > ws_size) return;  // workspace too small; fail loudly in validation

  float* zT   = y;                 // [768][6272], aliases y (y dead by kSGU)
  float* z    = y + 4816896;       // [6272][768]
  float* part = yT;                // 4*1605632 floats, aliases yT (dead by kOut)

  kLN1   <<<6272, 256, 0, stream>>>(x, g1, be1, xn);
  kExpand<<<1176, 256, 0, stream>>>(xn, W1, b1, y);
  kStats2<<<6272, 256, 0, stream>>>(y, stats);
  kTrans <<<2352, 256, 0, stream>>>(y, yT, 6272, 1536, stats, g2, be2);
  kSGU   <<<768,  256, 0, stream>>>(yT, W2, b2, zT);
  kTrans <<<1176, 256, 0, stream>>>(zT, z, 768, 6272, nullptr, nullptr, nullptr);
  kOut   <<<784,  256, 0, stream>>>(z, W3, part);
  kFinal <<<3136, 256, 0, stream>>>(part, x, b3, out);
}

// Round 4
// 244.900 us; speedup vs baseline: 1.5272x; 1.1446x over previous
//
#include <hip/hip_runtime.h>
#include <hip/hip_bf16.h>

#define DEV __device__ __forceinline__

typedef unsigned short u16;
typedef unsigned int   u32;
typedef __attribute__((ext_vector_type(8))) short bf16x8;
typedef __attribute__((ext_vector_type(4))) float f32x4;

DEV short bfbits(float f){
  __hip_bfloat16 h = __float2bfloat16(f);   // RNE; lowers to v_cvt_pk_bf16_f32 on gfx950
  return __builtin_bit_cast(short, h);
}
DEV u32 pk2(float lo, float hi){
  return (u32)(u16)bfbits(lo) | ((u32)(u16)bfbits(hi) << 16);
}

// all-thread block reduction (256 threads), returns totals in s, s2 for every thread
DEV void blockReduce2(float& s, float& s2, float* ps, float* ps2, int tid){
  #pragma unroll
  for (int o = 32; o > 0; o >>= 1){ s += __shfl_xor(s, o); s2 += __shfl_xor(s2, o); }
  int w = tid >> 6;
  if ((tid & 63) == 0){ ps[w] = s; ps2[w] = s2; }
  __syncthreads();
  s  = ps[0] + ps[1] + ps[2] + ps[3];
  s2 = ps2[0] + ps2[1] + ps2[2] + ps2[3];
}

// K0: LN1 over C=256 per (b,n) row. grid=6272, block=256
__global__ __launch_bounds__(256) void kLN1(const float* __restrict__ x, const float* __restrict__ g,
                                            const float* __restrict__ be, float* __restrict__ xn){
  __shared__ float ps[4], ps2[4];
  int bn = blockIdx.x, t = threadIdx.x;
  float v = x[(size_t)bn*256 + t];
  float s = v, s2 = v*v;
  blockReduce2(s, s2, ps, ps2, t);
  float m  = s * (1.f/256.f);
  float var = s2 * (1.f/256.f) - m*m;
  float rs = rsqrtf(var + 1e-3f);
  xn[(size_t)bn*256 + t] = (v - m)*rs*g[t] + be[t];
}

// K1 (MFMA): per-n GEMM [32x256]@[256x1536] + b1 + exact gelu -> y fp32.
// grid = 196*6, block = 256 (4 waves, each 64 e-cols). A: swizzled bf16 LDS.
// B: DIRECT global->register fragments (no LDS, no barriers in main loop).
__global__ __launch_bounds__(256) void kExpand(const float* __restrict__ xn, const float* __restrict__ W1,
                                               const float* __restrict__ b1, float* __restrict__ y){
  __shared__ unsigned char smA[16384];     // [32 b][256 k] bf16, 512 B pitch, XOR-swizzled
  int bid = blockIdx.x;
  int n = bid / 6, et = bid % 6;
  int tid = threadIdx.x;
  int e0 = et*256;

  // ---- stage A: xn[b][n][0..255] -> bf16 LDS, swizzled ----
  {
    int r = tid >> 3;                                  // batch row 0..31
    const float* src = xn + ((size_t)(r*196 + n))*256;
    #pragma unroll
    for (int i = 0; i < 4; ++i){
      int g = (tid & 7) + 8*i;                         // 16B-group 0..31
      int k0 = g*8;
      float4 a0 = *(const float4*)(src + k0);
      float4 a1 = *(const float4*)(src + k0 + 4);
      uint4 wv;
      wv.x = pk2(a0.x, a0.y); wv.y = pk2(a0.z, a0.w);
      wv.z = pk2(a1.x, a1.y); wv.w = pk2(a1.z, a1.w);
      int byte = r*512 + ((g*16) ^ ((r & 7) << 4));
      *(uint4*)(smA + byte) = wv;
    }
  }

  int w = tid >> 6, l = tid & 63;
  int col = e0 + w*64 + (l & 15);                      // this lane's base e-column
  int kb  = (l >> 4) * 8;                              // this lane's k-subblock
  const float* wb = W1 + (size_t)n*393216 + (size_t)kb*1536 + col;

  f32x4 acc[2][4];
  #pragma unroll
  for (int mt = 0; mt < 2; ++mt)
    #pragma unroll
    for (int nt = 0; nt < 4; ++nt)
      acc[mt][nt] = (f32x4){0.f, 0.f, 0.f, 0.f};

  float cur[4][8], nxt[4][8];
  #pragma unroll
  for (int nt = 0; nt < 4; ++nt)
    #pragma unroll
    for (int j = 0; j < 8; ++j)
      cur[nt][j] = wb[(size_t)j*1536 + nt*16];

  __syncthreads();                                     // A visible (only barrier)

  #pragma unroll
  for (int ks = 0; ks < 8; ++ks){
    if (ks < 7){
      const float* wn = wb + (size_t)(ks+1)*32*1536;
      #pragma unroll
      for (int nt = 0; nt < 4; ++nt)
        #pragma unroll
        for (int j = 0; j < 8; ++j)
          nxt[nt][j] = wn[(size_t)j*1536 + nt*16];
    }
    bf16x8 bfr[4];
    #pragma unroll
    for (int nt = 0; nt < 4; ++nt)
      #pragma unroll
      for (int j = 0; j < 8; ++j)
        bfr[nt][j] = bfbits(cur[nt][j]);
    bf16x8 afr[2];
    #pragma unroll
    for (int mt = 0; mt < 2; ++mt){
      int row = mt*16 + (l & 15);
      int kbyte = ks*64 + ((l >> 4) << 4);
      afr[mt] = *(const bf16x8*)(smA + row*512 + (kbyte ^ ((row & 7) << 4)));
    }
    #pragma unroll
    for (int mt = 0; mt < 2; ++mt)
      #pragma unroll
      for (int nt = 0; nt < 4; ++nt)
        acc[mt][nt] = __builtin_amdgcn_mfma_f32_16x16x32_bf16(afr[mt], bfr[nt], acc[mt][nt], 0, 0, 0);
    if (ks < 7){
      #pragma unroll
      for (int nt = 0; nt < 4; ++nt)
        #pragma unroll
        for (int j = 0; j < 8; ++j)
          cur[nt][j] = nxt[nt][j];
    }
  }

  // ---- epilogue: bias + exact gelu + store fp32 ----
  #pragma unroll
  for (int nt = 0; nt < 4; ++nt){
    int e = e0 + w*64 + nt*16 + (l & 15);
    float bb = b1[(size_t)n*1536 + e];
    #pragma unroll
    for (int mt = 0; mt < 2; ++mt){
      #pragma unroll
      for (int r = 0; r < 4; ++r){
        int b = mt*16 + ((l >> 4) << 2) + r;           // C/D: row=(lane>>4)*4+reg
        float v = acc[mt][nt][r] + bb;
        v = 0.5f*v*(1.f + erff(v*0.70710678118654752f));
        y[((size_t)(b*196 + n))*1536 + e] = v;
      }
    }
  }
}

// K2: LN2 stats over H=768 (u half of y) per (b,n). grid=6272, block=256
__global__ __launch_bounds__(256) void kStats2(const float* __restrict__ y, float2* __restrict__ stats){
  __shared__ float ps[4], ps2[4];
  int bn = blockIdx.x, t = threadIdx.x;
  const float* r = y + (size_t)bn*1536;
  float a0 = r[t], a1 = r[t+256], a2 = r[t+512];
  float s = a0+a1+a2, s2 = a0*a0 + a1*a1 + a2*a2;
  blockReduce2(s, s2, ps, ps2, t);
  float m   = s * (1.f/768.f);
  float var = s2 * (1.f/768.f) - m*m;
  if (t == 0) stats[bn] = make_float2(m, rsqrtf(var + 1e-3f));
}

// K3/K5: 64x64 tiled fp32 transpose [R rows x Cc cols] -> [Cc x R].
// If stats!=null, applies LN2 affine to columns c<768 (u half) while loading.
__global__ __launch_bounds__(256) void kTrans(const float* __restrict__ in, float* __restrict__ out,
                                              int R, int Cc, const float2* __restrict__ stats,
                                              const float* __restrict__ g2, const float* __restrict__ be2){
  __shared__ float T[64][65];
  int ntc = Cc >> 6;
  int rt = blockIdx.x / ntc, ct = blockIdx.x % ntc;
  int r0 = rt << 6, c0 = ct << 6;
  int l = threadIdx.x & 63, q = threadIdx.x >> 6;
  bool doLN = (stats != nullptr) && (c0 < 768);
  float gv = 1.f, bv = 0.f;
  if (doLN){ gv = g2[c0 + l]; bv = be2[c0 + l]; }
  #pragma unroll
  for (int i = 0; i < 16; ++i){
    int r = (i << 2) + q;
    float val = in[(size_t)(r0 + r)*Cc + c0 + l];
    if (doLN){ float2 st = stats[r0 + r]; val = (val - st.x)*st.y*gv + bv; }
    T[l][r] = val;
  }
  __syncthreads();
  #pragma unroll
  for (int i = 0; i < 16; ++i){
    int c = (i << 2) + q;
    out[(size_t)(c0 + c)*R + r0 + l] = T[c][l];
  }
}

// K4: per-d GEMM [32x196]@[196x196] + b2^T, times v -> zT. grid=768, block=256
__global__ __launch_bounds__(256) void kSGU(const float* __restrict__ yT, const float* __restrict__ W2,
                                            const float* __restrict__ b2, float* __restrict__ zT){
  __shared__ float A2[6272];
  int d = blockIdx.x, tid = threadIdx.x;
  const float* up = yT + (size_t)d*6272;
  for (int i = 0; i < 25; ++i){ int idx = i*256 + tid; if (idx < 6272) A2[idx] = up[idx]; }
  __syncthreads();
  if (tid < 196){
    const float* wp = W2 + (size_t)d*38416 + tid;   // 196*196
    float acc[32];
    #pragma unroll
    for (int b = 0; b < 32; ++b) acc[b] = 0.f;
    for (int m = 0; m < 196; m += 4){
      float w0 = wp[(m+0)*196];
      float w1 = wp[(m+1)*196];
      float w2v = wp[(m+2)*196];
      float w3 = wp[(m+3)*196];
      #pragma unroll
      for (int b = 0; b < 32; ++b){
        float4 a = *(const float4*)&A2[b*196 + m];
        acc[b] = fmaf(a.w, w3, fmaf(a.z, w2v, fmaf(a.y, w1, fmaf(a.x, w0, acc[b]))));
      }
    }
    float b2v = b2[(size_t)d*196 + tid];
    const float* vp = yT + (size_t)4816896 + (size_t)d*6272 + tid;   // v half: rows 768..1535
    float* zp = zT + (size_t)d*6272 + tid;
    #pragma unroll
    for (int b = 0; b < 32; ++b){
      float u2 = acc[b] + b2v;
      float vv = vp[b*196];
      zp[b*196] = u2*vv;
    }
  }
}

// K6 (MFMA): per-(n, d-quarter) GEMM [32x192]@[192x256] -> fp32 partials.
// grid=196*4, block=256 (4 waves x 64 c-cols). A: swizzled bf16 LDS (12 KB).
// B: direct global->register fragments.
__global__ __launch_bounds__(256) void kOut(const float* __restrict__ z, const float* __restrict__ W3,
                                            float* __restrict__ part){
  __shared__ unsigned char smA[12288];     // [32 b][192 d] bf16, 384 B pitch, swizzled
  int bid = blockIdx.x;
  int n = bid >> 2, h = bid & 3;
  int tid = threadIdx.x;

  // ---- stage A: z[b][n*768 + h*192 .. +192] -> bf16 LDS ----
  {
    int r = tid >> 3;
    const float* src = z + ((size_t)(r*196 + n))*768 + h*192;
    #pragma unroll
    for (int i = 0; i < 3; ++i){
      int g = (tid & 7) + 8*i;                         // 16B-group 0..23
      int k0 = g*8;
      float4 a0 = *(const float4*)(src + k0);
      float4 a1 = *(const float4*)(src + k0 + 4);
      uint4 wv;
      wv.x = pk2(a0.x, a0.y); wv.y = pk2(a0.z, a0.w);
      wv.z = pk2(a1.x, a1.y); wv.w = pk2(a1.z, a1.w);
      int byte = r*384 + ((g*16) ^ ((r & 7) << 4));
      *(uint4*)(smA + byte) = wv;
    }
  }

  int w = tid >> 6, l = tid & 63;
  int col = w*64 + (l & 15);
  int kb  = (l >> 4) * 8;
  const float* wb = W3 + (size_t)n*196608 + (size_t)(h*192 + kb)*256 + col;

  f32x4 acc[2][4];
  #pragma unroll
  for (int mt = 0; mt < 2; ++mt)
    #pragma unroll
    for (int nt = 0; nt < 4; ++nt)
      acc[mt][nt] = (f32x4){0.f, 0.f, 0.f, 0.f};

  float cur[4][8], nxt[4][8];
  #pragma unroll
  for (int nt = 0; nt < 4; ++nt)
    #pragma unroll
    for (int j = 0; j < 8; ++j)
      cur[nt][j] = wb[(size_t)j*256 + nt*16];

  __syncthreads();

  #pragma unroll
  for (int ks = 0; ks < 6; ++ks){
    if (ks < 5){
      const float* wn = wb + (size_t)(ks+1)*32*256;
      #pragma unroll
      for (int nt = 0; nt < 4; ++nt)
        #pragma unroll
        for (int j = 0; j < 8; ++j)
          nxt[nt][j] = wn[(size_t)j*256 + nt*16];
    }
    bf16x8 bfr[4];
    #pragma unroll
    for (int nt = 0; nt < 4; ++nt)
      #pragma unroll
      for (int j = 0; j < 8; ++j)
        bfr[nt][j] = bfbits(cur[nt][j]);
    bf16x8 afr[2];
    #pragma unroll
    for (int mt = 0; mt < 2; ++mt){
      int row = mt*16 + (l & 15);
      int kbyte = ks*64 + ((l >> 4) << 4);
      afr[mt] = *(const bf16x8*)(smA + row*384 + (kbyte ^ ((row & 7) << 4)));
    }
    #pragma unroll
    for (int mt = 0; mt < 2; ++mt)
      #pragma unroll
      for (int nt = 0; nt < 4; ++nt)
        acc[mt][nt] = __builtin_amdgcn_mfma_f32_16x16x32_bf16(afr[mt], bfr[nt], acc[mt][nt], 0, 0, 0);
    if (ks < 5){
      #pragma unroll
      for (int nt = 0; nt < 4; ++nt)
        #pragma unroll
        for (int j = 0; j < 8; ++j)
          cur[nt][j] = nxt[nt][j];
    }
  }

  // ---- epilogue: write fp32 partials (layout: part[h][b][n][c]) ----
  #pragma unroll
  for (int nt = 0; nt < 4; ++nt){
    int c = w*64 + nt*16 + (l & 15);
    #pragma unroll
    for (int mt = 0; mt < 2; ++mt){
      #pragma unroll
      for (int r = 0; r < 4; ++r){
        int b = mt*16 + ((l >> 4) << 2) + r;
        part[(size_t)h*1605632 + (size_t)b*50176 + (size_t)n*256 + c] = acc[mt][nt][r];
      }
    }
  }
}

// K7: out = sum of 4 partials + b3 + x. grid=3136, block=256 (2 elems/thread)
__global__ __launch_bounds__(256) void kFinal(const float* __restrict__ part, const float* __restrict__ x,
                                              const float* __restrict__ b3, float* __restrict__ out){
  int i2 = blockIdx.x*256 + threadIdx.x;     // pair index < 802816
  size_t idx = (size_t)i2 * 2;
  const float2* p = (const float2*)part;
  float2 s0 = p[i2];
  float2 s1 = p[i2 + 802816];
  float2 s2 = p[i2 + 2*802816];
  float2 s3 = p[i2 + 3*802816];
  float lo = s0.x + s1.x + s2.x + s3.x;
  float hi = s0.y + s1.y + s2.y + s3.y;
  float2 xv = ((const float2*)x)[i2];
  unsigned int r = (unsigned int)(idx % 50176);   // b3 repeats per batch; r is even
  float2 bv = *(const float2*)(b3 + r);
  lo += xv.x + bv.x;
  hi += xv.y + bv.y;
  ((float2*)out)[i2] = make_float2(lo, hi);
}

extern "C" void kernel_launch(void* const* d_in, const int* in_sizes, int n_in,
                              void* d_out, int out_size, void* d_ws, size_t ws_size,
                              hipStream_t stream){
  const float* x   = (const float*)d_in[0];
  const float* g1  = (const float*)d_in[1];
  const float* be1 = (const float*)d_in[2];
  const float* W1  = (const float*)d_in[3];
  const float* b1  = (const float*)d_in[4];
  const float* g2  = (const float*)d_in[5];
  const float* be2 = (const float*)d_in[6];
  const float* W2  = (const float*)d_in[7];
  const float* b2  = (const float*)d_in[8];
  const float* W3  = (const float*)d_in[9];
  const float* b3  = (const float*)d_in[10];
  float* out = (float*)d_out;

  char* ws = (char*)d_ws;
  size_t off = 0;
  auto alloc = [&](size_t bytes) -> void* {
    void* p = ws + off;
    off += (bytes + 255) & ~(size_t)255;
    return p;
  };
  // Region A: xn (dead after kExpand)
  float*  xn    = (float*) alloc((size_t)1605632*4);
  // Region B: y [6272][1536] (dead after kTrans1); later reused for zT + z
  float*  y     = (float*) alloc((size_t)9633792*4);
  // Region C: LN2 stats
  float2* stats = (float2*)alloc((size_t)6272*8);
  // Region D: yT [1536][6272] (dead after kSGU); later reused for part
  float*  yT    = (float*) alloc((size_t)9633792*4);
  if (off > ws_size) return;  // workspace too small; fail loudly in validation

  float* zT   = y;                 // [768][6272], aliases y (y dead by kSGU)
  float* z    = y + 4816896;       // [6272][768]
  float* part = yT;                // 4*1605632 floats, aliases yT (dead by kOut)

  kLN1   <<<6272, 256, 0, stream>>>(x, g1, be1, xn);
  kExpand<<<1176, 256, 0, stream>>>(xn, W1, b1, y);
  kStats2<<<6272, 256, 0, stream>>>(y, stats);
  kTrans <<<2352, 256, 0, stream>>>(y, yT, 6272, 1536, stats, g2, be2);
  kSGU   <<<768,  256, 0, stream>>>(yT, W2, b2, zT);
  kTrans <<<1176, 256, 0, stream>>>(zT, z, 768, 6272, nullptr, nullptr, nullptr);
  kOut   <<<784,  256, 0, stream>>>(z, W3, part);
  kFinal <<<3136, 256, 0, stream>>>(part, x, b3, out);
}

// Round 5
// 211.492 us; speedup vs baseline: 1.7684x; 1.1580x over previous
//
#include <hip/hip_runtime.h>
#include <hip/hip_bf16.h>

#define DEV __device__ __forceinline__

typedef unsigned short u16;
typedef unsigned int   u32;
typedef __attribute__((ext_vector_type(8))) short bf16x8;
typedef __attribute__((ext_vector_type(4))) float f32x4;

DEV short bfbits(float f){
  __hip_bfloat16 h = __float2bfloat16(f);   // RNE; lowers to v_cvt_pk_bf16_f32 on gfx950
  return __builtin_bit_cast(short, h);
}
DEV u32 pk2(float lo, float hi){
  return (u32)(u16)bfbits(lo) | ((u32)(u16)bfbits(hi) << 16);
}

// all-thread block reduction (256 threads), returns totals in s, s2 for every thread
DEV void blockReduce2(float& s, float& s2, float* ps, float* ps2, int tid){
  #pragma unroll
  for (int o = 32; o > 0; o >>= 1){ s += __shfl_xor(s, o); s2 += __shfl_xor(s2, o); }
  int w = tid >> 6;
  if ((tid & 63) == 0){ ps[w] = s; ps2[w] = s2; }
  __syncthreads();
  s  = ps[0] + ps[1] + ps[2] + ps[3];
  s2 = ps2[0] + ps2[1] + ps2[2] + ps2[3];
}

// K0: LN1 over C=256 per (b,n) row. grid=6272, block=256
__global__ __launch_bounds__(256) void kLN1(const float* __restrict__ x, const float* __restrict__ g,
                                            const float* __restrict__ be, float* __restrict__ xn){
  __shared__ float ps[4], ps2[4];
  int bn = blockIdx.x, t = threadIdx.x;
  float v = x[(size_t)bn*256 + t];
  float s = v, s2 = v*v;
  blockReduce2(s, s2, ps, ps2, t);
  float m  = s * (1.f/256.f);
  float var = s2 * (1.f/256.f) - m*m;
  float rs = rsqrtf(var + 1e-3f);
  xn[(size_t)bn*256 + t] = (v - m)*rs*g[t] + be[t];
}

// K1 (MFMA): per-n GEMM [32x256]@[256x1536] + b1 + exact gelu -> y fp32.
// grid = 196*6, block = 256 (4 waves, each 64 e-cols). A: swizzled bf16 LDS.
// B: DIRECT global->register fragments (no LDS, no barriers in main loop).
__global__ __launch_bounds__(256) void kExpand(const float* __restrict__ xn, const float* __restrict__ W1,
                                               const float* __restrict__ b1, float* __restrict__ y){
  __shared__ unsigned char smA[16384];     // [32 b][256 k] bf16, 512 B pitch, XOR-swizzled
  int bid = blockIdx.x;
  int n = bid / 6, et = bid % 6;
  int tid = threadIdx.x;
  int e0 = et*256;

  // ---- stage A: xn[b][n][0..255] -> bf16 LDS, swizzled ----
  {
    int r = tid >> 3;                                  // batch row 0..31
    const float* src = xn + ((size_t)(r*196 + n))*256;
    #pragma unroll
    for (int i = 0; i < 4; ++i){
      int g = (tid & 7) + 8*i;                         // 16B-group 0..31
      int k0 = g*8;
      float4 a0 = *(const float4*)(src + k0);
      float4 a1 = *(const float4*)(src + k0 + 4);
      uint4 wv;
      wv.x = pk2(a0.x, a0.y); wv.y = pk2(a0.z, a0.w);
      wv.z = pk2(a1.x, a1.y); wv.w = pk2(a1.z, a1.w);
      int byte = r*512 + ((g*16) ^ ((r & 7) << 4));
      *(uint4*)(smA + byte) = wv;
    }
  }

  int w = tid >> 6, l = tid & 63;
  int col = e0 + w*64 + (l & 15);                      // this lane's base e-column
  int kb  = (l >> 4) * 8;                              // this lane's k-subblock
  const float* wb = W1 + (size_t)n*393216 + (size_t)kb*1536 + col;

  f32x4 acc[2][4];
  #pragma unroll
  for (int mt = 0; mt < 2; ++mt)
    #pragma unroll
    for (int nt = 0; nt < 4; ++nt)
      acc[mt][nt] = (f32x4){0.f, 0.f, 0.f, 0.f};

  float cur[4][8], nxt[4][8];
  #pragma unroll
  for (int nt = 0; nt < 4; ++nt)
    #pragma unroll
    for (int j = 0; j < 8; ++j)
      cur[nt][j] = wb[(size_t)j*1536 + nt*16];

  __syncthreads();                                     // A visible (only barrier)

  #pragma unroll
  for (int ks = 0; ks < 8; ++ks){
    if (ks < 7){
      const float* wn = wb + (size_t)(ks+1)*32*1536;
      #pragma unroll
      for (int nt = 0; nt < 4; ++nt)
        #pragma unroll
        for (int j = 0; j < 8; ++j)
          nxt[nt][j] = wn[(size_t)j*1536 + nt*16];
    }
    bf16x8 bfr[4];
    #pragma unroll
    for (int nt = 0; nt < 4; ++nt)
      #pragma unroll
      for (int j = 0; j < 8; ++j)
        bfr[nt][j] = bfbits(cur[nt][j]);
    bf16x8 afr[2];
    #pragma unroll
    for (int mt = 0; mt < 2; ++mt){
      int row = mt*16 + (l & 15);
      int kbyte = ks*64 + ((l >> 4) << 4);
      afr[mt] = *(const bf16x8*)(smA + row*512 + (kbyte ^ ((row & 7) << 4)));
    }
    #pragma unroll
    for (int mt = 0; mt < 2; ++mt)
      #pragma unroll
      for (int nt = 0; nt < 4; ++nt)
        acc[mt][nt] = __builtin_amdgcn_mfma_f32_16x16x32_bf16(afr[mt], bfr[nt], acc[mt][nt], 0, 0, 0);
    if (ks < 7){
      #pragma unroll
      for (int nt = 0; nt < 4; ++nt)
        #pragma unroll
        for (int j = 0; j < 8; ++j)
          cur[nt][j] = nxt[nt][j];
    }
  }

  // ---- epilogue: bias + exact gelu + store fp32 ----
  #pragma unroll
  for (int nt = 0; nt < 4; ++nt){
    int e = e0 + w*64 + nt*16 + (l & 15);
    float bb = b1[(size_t)n*1536 + e];
    #pragma unroll
    for (int mt = 0; mt < 2; ++mt){
      #pragma unroll
      for (int r = 0; r < 4; ++r){
        int b = mt*16 + ((l >> 4) << 2) + r;           // C/D: row=(lane>>4)*4+reg
        float v = acc[mt][nt][r] + bb;
        v = 0.5f*v*(1.f + erff(v*0.70710678118654752f));
        y[((size_t)(b*196 + n))*1536 + e] = v;
      }
    }
  }
}

// K2: LN2 stats over H=768 (u half of y) per (b,n). grid=6272, block=256
__global__ __launch_bounds__(256) void kStats2(const float* __restrict__ y, float2* __restrict__ stats){
  __shared__ float ps[4], ps2[4];
  int bn = blockIdx.x, t = threadIdx.x;
  const float* r = y + (size_t)bn*1536;
  float a0 = r[t], a1 = r[t+256], a2 = r[t+512];
  float s = a0+a1+a2, s2 = a0*a0 + a1*a1 + a2*a2;
  blockReduce2(s, s2, ps, ps2, t);
  float m   = s * (1.f/768.f);
  float var = s2 * (1.f/768.f) - m*m;
  if (t == 0) stats[bn] = make_float2(m, rsqrtf(var + 1e-3f));
}

// K3/K5: 64x64 tiled fp32 transpose [R rows x Cc cols] -> [Cc x R].
// If stats!=null, applies LN2 affine to columns c<768 (u half) while loading.
__global__ __launch_bounds__(256) void kTrans(const float* __restrict__ in, float* __restrict__ out,
                                              int R, int Cc, const float2* __restrict__ stats,
                                              const float* __restrict__ g2, const float* __restrict__ be2){
  __shared__ float T[64][65];
  int ntc = Cc >> 6;
  int rt = blockIdx.x / ntc, ct = blockIdx.x % ntc;
  int r0 = rt << 6, c0 = ct << 6;
  int l = threadIdx.x & 63, q = threadIdx.x >> 6;
  bool doLN = (stats != nullptr) && (c0 < 768);
  float gv = 1.f, bv = 0.f;
  if (doLN){ gv = g2[c0 + l]; bv = be2[c0 + l]; }
  #pragma unroll
  for (int i = 0; i < 16; ++i){
    int r = (i << 2) + q;
    float val = in[(size_t)(r0 + r)*Cc + c0 + l];
    if (doLN){ float2 st = stats[r0 + r]; val = (val - st.x)*st.y*gv + bv; }
    T[l][r] = val;
  }
  __syncthreads();
  #pragma unroll
  for (int i = 0; i < 16; ++i){
    int c = (i << 2) + q;
    out[(size_t)(c0 + c)*R + r0 + l] = T[c][l];
  }
}

// K4 (MFMA): per-d GEMM [32(b) x 196(m)] @ W2[d][196 x 196] + b2^T, times v -> zT.
// grid=768, block=256 (4 waves). A: u^T[d] swizzled bf16 LDS, K padded 196->224 (zeros).
// B: direct global->register fragments, predicated (k<196, n<196).
// Wave w owns n-tiles {w, w+4, w+8, w+12(<13)}.
__global__ __launch_bounds__(256) void kSGU(const float* __restrict__ yT, const float* __restrict__ W2,
                                            const float* __restrict__ b2, float* __restrict__ zT){
  __shared__ unsigned char smA[16384];     // [32 b][256 m] bf16, 512 B pitch, swizzled
  int d = blockIdx.x, tid = threadIdx.x;
  const float* up = yT + (size_t)d*6272;   // u^T[d]: [32 b][196 m]

  // ---- stage A (predicated m<196, zero-padded to 256) ----
  {
    int r = tid >> 3;                                  // b row 0..31
    const float* src = up + r*196;
    #pragma unroll
    for (int i = 0; i < 4; ++i){
      int g = (tid & 7) + 8*i;                         // 16B group (8 m-elems)
      int k0 = g*8;
      float a[8];
      if (k0 + 8 <= 196){
        float4 a0 = *(const float4*)(src + k0);
        float4 a1 = *(const float4*)(src + k0 + 4);
        a[0]=a0.x; a[1]=a0.y; a[2]=a0.z; a[3]=a0.w;
        a[4]=a1.x; a[5]=a1.y; a[6]=a1.z; a[7]=a1.w;
      } else {
        #pragma unroll
        for (int j = 0; j < 8; ++j){
          int k = k0 + j;
          a[j] = (k < 196) ? src[k] : 0.f;
        }
      }
      uint4 wv;
      wv.x = pk2(a[0],a[1]); wv.y = pk2(a[2],a[3]);
      wv.z = pk2(a[4],a[5]); wv.w = pk2(a[6],a[7]);
      int byte = r*512 + ((g*16) ^ ((r & 7) << 4));
      *(uint4*)(smA + byte) = wv;
    }
  }

  int w = tid >> 6, l = tid & 63;
  int kb = (l >> 4) * 8;                               // k-subblock within k-step

  f32x4 acc[2][4];
  #pragma unroll
  for (int mt = 0; mt < 2; ++mt)
    #pragma unroll
    for (int t = 0; t < 4; ++t)
      acc[mt][t] = (f32x4){0.f, 0.f, 0.f, 0.f};

  // per-tile column info
  int  ncol[4]; bool nok[4];
  const float* wbs[4];
  #pragma unroll
  for (int t = 0; t < 4; ++t){
    int ntg = w + 4*t;
    int n = ntg*16 + (l & 15);
    ncol[t] = n;
    nok[t] = (ntg < 13) && (n < 196);
    wbs[t] = W2 + (size_t)d*38416 + (n < 196 ? n : 195);
  }

  __syncthreads();

  for (int ks = 0; ks < 7; ++ks){
    bf16x8 afr[2];
    #pragma unroll
    for (int mt = 0; mt < 2; ++mt){
      int row = mt*16 + (l & 15);
      int kbyte = ks*64 + ((l >> 4) << 4);
      afr[mt] = *(const bf16x8*)(smA + row*512 + (kbyte ^ ((row & 7) << 4)));
    }
    #pragma unroll
    for (int t = 0; t < 4; ++t){
      if (w + 4*t >= 13) continue;                     // wave-uniform skip
      bf16x8 bfr;
      #pragma unroll
      for (int j = 0; j < 8; ++j){
        int k = ks*32 + kb + j;
        float wv = wbs[t][(size_t)(k < 196 ? k : 195)*196];
        bfr[j] = bfbits((nok[t] && k < 196) ? wv : 0.f);
      }
      acc[0][t] = __builtin_amdgcn_mfma_f32_16x16x32_bf16(afr[0], bfr, acc[0][t], 0, 0, 0);
      acc[1][t] = __builtin_amdgcn_mfma_f32_16x16x32_bf16(afr[1], bfr, acc[1][t], 0, 0, 0);
    }
  }

  // ---- epilogue: +b2^T, *v, store zT[d][b*196+n] ----
  #pragma unroll
  for (int t = 0; t < 4; ++t){
    if (!nok[t]) continue;
    int n = ncol[t];
    float b2v = b2[(size_t)d*196 + n];
    const float* vp = yT + (size_t)4816896 + (size_t)d*6272 + n;   // v half
    float* zp = zT + (size_t)d*6272 + n;
    #pragma unroll
    for (int mt = 0; mt < 2; ++mt){
      #pragma unroll
      for (int r = 0; r < 4; ++r){
        int b = mt*16 + ((l >> 4) << 2) + r;
        float u2 = acc[mt][t][r] + b2v;
        zp[(size_t)b*196] = u2 * vp[(size_t)b*196];
      }
    }
  }
}

// K6 (MFMA): per-(n, d-quarter) GEMM [32x192]@[192x256] -> fp32 partials.
// grid=196*4, block=256 (4 waves x 64 c-cols). A: swizzled bf16 LDS (12 KB).
// B: direct global->register fragments.
__global__ __launch_bounds__(256) void kOut(const float* __restrict__ z, const float* __restrict__ W3,
                                            float* __restrict__ part){
  __shared__ unsigned char smA[12288];     // [32 b][192 d] bf16, 384 B pitch, swizzled
  int bid = blockIdx.x;
  int n = bid >> 2, h = bid & 3;
  int tid = threadIdx.x;

  // ---- stage A: z[b][n*768 + h*192 .. +192] -> bf16 LDS ----
  {
    int r = tid >> 3;
    const float* src = z + ((size_t)(r*196 + n))*768 + h*192;
    #pragma unroll
    for (int i = 0; i < 3; ++i){
      int g = (tid & 7) + 8*i;                         // 16B-group 0..23
      int k0 = g*8;
      float4 a0 = *(const float4*)(src + k0);
      float4 a1 = *(const float4*)(src + k0 + 4);
      uint4 wv;
      wv.x = pk2(a0.x, a0.y); wv.y = pk2(a0.z, a0.w);
      wv.z = pk2(a1.x, a1.y); wv.w = pk2(a1.z, a1.w);
      int byte = r*384 + ((g*16) ^ ((r & 7) << 4));
      *(uint4*)(smA + byte) = wv;
    }
  }

  int w = tid >> 6, l = tid & 63;
  int col = w*64 + (l & 15);
  int kb  = (l >> 4) * 8;
  const float* wb = W3 + (size_t)n*196608 + (size_t)(h*192 + kb)*256 + col;

  f32x4 acc[2][4];
  #pragma unroll
  for (int mt = 0; mt < 2; ++mt)
    #pragma unroll
    for (int nt = 0; nt < 4; ++nt)
      acc[mt][nt] = (f32x4){0.f, 0.f, 0.f, 0.f};

  float cur[4][8], nxt[4][8];
  #pragma unroll
  for (int nt = 0; nt < 4; ++nt)
    #pragma unroll
    for (int j = 0; j < 8; ++j)
      cur[nt][j] = wb[(size_t)j*256 + nt*16];

  __syncthreads();

  #pragma unroll
  for (int ks = 0; ks < 6; ++ks){
    if (ks < 5){
      const float* wn = wb + (size_t)(ks+1)*32*256;
      #pragma unroll
      for (int nt = 0; nt < 4; ++nt)
        #pragma unroll
        for (int j = 0; j < 8; ++j)
          nxt[nt][j] = wn[(size_t)j*256 + nt*16];
    }
    bf16x8 bfr[4];
    #pragma unroll
    for (int nt = 0; nt < 4; ++nt)
      #pragma unroll
      for (int j = 0; j < 8; ++j)
        bfr[nt][j] = bfbits(cur[nt][j]);
    bf16x8 afr[2];
    #pragma unroll
    for (int mt = 0; mt < 2; ++mt){
      int row = mt*16 + (l & 15);
      int kbyte = ks*64 + ((l >> 4) << 4);
      afr[mt] = *(const bf16x8*)(smA + row*384 + (kbyte ^ ((row & 7) << 4)));
    }
    #pragma unroll
    for (int mt = 0; mt < 2; ++mt)
      #pragma unroll
      for (int nt = 0; nt < 4; ++nt)
        acc[mt][nt] = __builtin_amdgcn_mfma_f32_16x16x32_bf16(afr[mt], bfr[nt], acc[mt][nt], 0, 0, 0);
    if (ks < 5){
      #pragma unroll
      for (int nt = 0; nt < 4; ++nt)
        #pragma unroll
        for (int j = 0; j < 8; ++j)
          cur[nt][j] = nxt[nt][j];
    }
  }

  // ---- epilogue: write fp32 partials (layout: part[h][b][n][c]) ----
  #pragma unroll
  for (int nt = 0; nt < 4; ++nt){
    int c = w*64 + nt*16 + (l & 15);
    #pragma unroll
    for (int mt = 0; mt < 2; ++mt){
      #pragma unroll
      for (int r = 0; r < 4; ++r){
        int b = mt*16 + ((l >> 4) << 2) + r;
        part[(size_t)h*1605632 + (size_t)b*50176 + (size_t)n*256 + c] = acc[mt][nt][r];
      }
    }
  }
}

// K7: out = sum of 4 partials + b3 + x. grid=3136, block=256 (2 elems/thread)
__global__ __launch_bounds__(256) void kFinal(const float* __restrict__ part, const float* __restrict__ x,
                                              const float* __restrict__ b3, float* __restrict__ out){
  int i2 = blockIdx.x*256 + threadIdx.x;     // pair index < 802816
  size_t idx = (size_t)i2 * 2;
  const float2* p = (const float2*)part;
  float2 s0 = p[i2];
  float2 s1 = p[i2 + 802816];
  float2 s2 = p[i2 + 2*802816];
  float2 s3 = p[i2 + 3*802816];
  float lo = s0.x + s1.x + s2.x + s3.x;
  float hi = s0.y + s1.y + s2.y + s3.y;
  float2 xv = ((const float2*)x)[i2];
  unsigned int r = (unsigned int)(idx % 50176);   // b3 repeats per batch; r is even
  float2 bv = *(const float2*)(b3 + r);
  lo += xv.x + bv.x;
  hi += xv.y + bv.y;
  ((float2*)out)[i2] = make_float2(lo, hi);
}

extern "C" void kernel_launch(void* const* d_in, const int* in_sizes, int n_in,
                              void* d_out, int out_size, void* d_ws, size_t ws_size,
                              hipStream_t stream){
  const float* x   = (const float*)d_in[0];
  const float* g1  = (const float*)d_in[1];
  const float* be1 = (const float*)d_in[2];
  const float* W1  = (const float*)d_in[3];
  const float* b1  = (const float*)d_in[4];
  const float* g2  = (const float*)d_in[5];
  const float* be2 = (const float*)d_in[6];
  const float* W2  = (const float*)d_in[7];
  const float* b2  = (const float*)d_in[8];
  const float* W3  = (const float*)d_in[9];
  const float* b3  = (const float*)d_in[10];
  float* out = (float*)d_out;

  char* ws = (char*)d_ws;
  size_t off = 0;
  auto alloc = [&](size_t bytes) -> void* {
    void* p = ws + off;
    off += (bytes + 255) & ~(size_t)255;
    return p;
  };
  // Region A: xn (dead after kExpand)
  float*  xn    = (float*) alloc((size_t)1605632*4);
  // Region B: y [6272][1536] (dead after kTrans1); later reused for zT + z
  float*  y     = (float*) alloc((size_t)9633792*4);
  // Region C: LN2 stats
  float2* stats = (float2*)alloc((size_t)6272*8);
  // Region D: yT [1536][6272] (dead after kSGU); later reused for part
  float*  yT    = (float*) alloc((size_t)9633792*4);
  if (off > ws_size) return;  // workspace too small; fail loudly in validation

  float* zT   = y;                 // [768][6272], aliases y (y dead by kSGU)
  float* z    = y + 4816896;       // [6272][768]
  float* part = yT;                // 4*1605632 floats, aliases yT (dead by kOut)

  kLN1   <<<6272, 256, 0, stream>>>(x, g1, be1, xn);
  kExpand<<<1176, 256, 0, stream>>>(xn, W1, b1, y);
  kStats2<<<6272, 256, 0, stream>>>(y, stats);
  kTrans <<<2352, 256, 0, stream>>>(y, yT, 6272, 1536, stats, g2, be2);
  kSGU   <<<768,  256, 0, stream>>>(yT, W2, b2, zT);
  kTrans <<<1176, 256, 0, stream>>>(zT, z, 768, 6272, nullptr, nullptr, nullptr);
  kOut   <<<784,  256, 0, stream>>>(z, W3, part);
  kFinal <<<3136, 256, 0, stream>>>(part, x, b3, out);
}

// Round 6
// 204.741 us; speedup vs baseline: 1.8267x; 1.0330x over previous
//
#include <hip/hip_runtime.h>
#include <hip/hip_bf16.h>

#define DEV __device__ __forceinline__

typedef unsigned short u16;
typedef unsigned int   u32;
typedef __attribute__((ext_vector_type(8))) short bf16x8;
typedef __attribute__((ext_vector_type(4))) float f32x4;

DEV float bf2f(u16 v){ u32 u = ((u32)v) << 16; return __uint_as_float(u); }
DEV short bfbits(float f){
  __hip_bfloat16 h = __float2bfloat16(f);   // RNE; lowers to v_cvt_pk_bf16_f32 on gfx950
  return __builtin_bit_cast(short, h);
}
DEV u16 f2bf(float f){ return (u16)bfbits(f); }
DEV u32 pk2(float lo, float hi){
  return (u32)f2bf(lo) | ((u32)f2bf(hi) << 16);
}

// all-thread block reduction (256 threads), returns totals in s, s2 for every thread
DEV void blockReduce2(float& s, float& s2, float* ps, float* ps2, int tid){
  #pragma unroll
  for (int o = 32; o > 0; o >>= 1){ s += __shfl_xor(s, o); s2 += __shfl_xor(s2, o); }
  int w = tid >> 6;
  if ((tid & 63) == 0){ ps[w] = s; ps2[w] = s2; }
  __syncthreads();
  s  = ps[0] + ps[1] + ps[2] + ps[3];
  s2 = ps2[0] + ps2[1] + ps2[2] + ps2[3];
}

// K0: LN1 over C=256 per (b,n) row. grid=6272, block=256. out: bf16
__global__ __launch_bounds__(256) void kLN1(const float* __restrict__ x, const float* __restrict__ g,
                                            const float* __restrict__ be, u16* __restrict__ xn){
  __shared__ float ps[4], ps2[4];
  int bn = blockIdx.x, t = threadIdx.x;
  float v = x[(size_t)bn*256 + t];
  float s = v, s2 = v*v;
  blockReduce2(s, s2, ps, ps2, t);
  float m  = s * (1.f/256.f);
  float var = s2 * (1.f/256.f) - m*m;
  float rs = rsqrtf(var + 1e-3f);
  xn[(size_t)bn*256 + t] = f2bf((v - m)*rs*g[t] + be[t]);
}

// K1 (MFMA): per-n GEMM [32x256]@[256x1536] + b1 + exact gelu -> y bf16.
// grid = 196*6, block = 256 (4 waves, each 64 e-cols). A: swizzled bf16 LDS (pure copy).
// B: DIRECT global->register fragments (no LDS, no barriers in main loop).
__global__ __launch_bounds__(256) void kExpand(const u16* __restrict__ xn, const float* __restrict__ W1,
                                               const float* __restrict__ b1, u16* __restrict__ y){
  __shared__ unsigned char smA[16384];     // [32 b][256 k] bf16, 512 B pitch, XOR-swizzled
  int bid = blockIdx.x;
  int n = bid / 6, et = bid % 6;
  int tid = threadIdx.x;
  int e0 = et*256;

  // ---- stage A: xn[b][n][0..255] bf16 -> LDS, swizzled (copy only) ----
  {
    int r = tid >> 3;                                  // batch row 0..31
    const unsigned char* src = (const unsigned char*)(xn + ((size_t)(r*196 + n))*256);
    #pragma unroll
    for (int i = 0; i < 4; ++i){
      int g = (tid & 7) + 8*i;                         // 16B-group 0..31 (8 bf16)
      uint4 wv = *(const uint4*)(src + g*16);
      int byte = r*512 + ((g*16) ^ ((r & 7) << 4));
      *(uint4*)(smA + byte) = wv;
    }
  }

  int w = tid >> 6, l = tid & 63;
  int col = e0 + w*64 + (l & 15);                      // this lane's base e-column
  int kb  = (l >> 4) * 8;                              // this lane's k-subblock
  const float* wb = W1 + (size_t)n*393216 + (size_t)kb*1536 + col;

  f32x4 acc[2][4];
  #pragma unroll
  for (int mt = 0; mt < 2; ++mt)
    #pragma unroll
    for (int nt = 0; nt < 4; ++nt)
      acc[mt][nt] = (f32x4){0.f, 0.f, 0.f, 0.f};

  float cur[4][8], nxt[4][8];
  #pragma unroll
  for (int nt = 0; nt < 4; ++nt)
    #pragma unroll
    for (int j = 0; j < 8; ++j)
      cur[nt][j] = wb[(size_t)j*1536 + nt*16];

  __syncthreads();                                     // A visible (only barrier)

  #pragma unroll
  for (int ks = 0; ks < 8; ++ks){
    if (ks < 7){
      const float* wn = wb + (size_t)(ks+1)*32*1536;
      #pragma unroll
      for (int nt = 0; nt < 4; ++nt)
        #pragma unroll
        for (int j = 0; j < 8; ++j)
          nxt[nt][j] = wn[(size_t)j*1536 + nt*16];
    }
    bf16x8 bfr[4];
    #pragma unroll
    for (int nt = 0; nt < 4; ++nt)
      #pragma unroll
      for (int j = 0; j < 8; ++j)
        bfr[nt][j] = bfbits(cur[nt][j]);
    bf16x8 afr[2];
    #pragma unroll
    for (int mt = 0; mt < 2; ++mt){
      int row = mt*16 + (l & 15);
      int kbyte = ks*64 + ((l >> 4) << 4);
      afr[mt] = *(const bf16x8*)(smA + row*512 + (kbyte ^ ((row & 7) << 4)));
    }
    #pragma unroll
    for (int mt = 0; mt < 2; ++mt)
      #pragma unroll
      for (int nt = 0; nt < 4; ++nt)
        acc[mt][nt] = __builtin_amdgcn_mfma_f32_16x16x32_bf16(afr[mt], bfr[nt], acc[mt][nt], 0, 0, 0);
    if (ks < 7){
      #pragma unroll
      for (int nt = 0; nt < 4; ++nt)
        #pragma unroll
        for (int j = 0; j < 8; ++j)
          cur[nt][j] = nxt[nt][j];
    }
  }

  // ---- epilogue: bias + exact gelu + store bf16 ----
  #pragma unroll
  for (int nt = 0; nt < 4; ++nt){
    int e = e0 + w*64 + nt*16 + (l & 15);
    float bb = b1[(size_t)n*1536 + e];
    #pragma unroll
    for (int mt = 0; mt < 2; ++mt){
      #pragma unroll
      for (int r = 0; r < 4; ++r){
        int b = mt*16 + ((l >> 4) << 2) + r;           // C/D: row=(lane>>4)*4+reg
        float v = acc[mt][nt][r] + bb;
        v = 0.5f*v*(1.f + erff(v*0.70710678118654752f));
        y[((size_t)(b*196 + n))*1536 + e] = f2bf(v);
      }
    }
  }
}

// K2: LN2 stats over H=768 (u half of y bf16) per (b,n). grid=6272, block=256
__global__ __launch_bounds__(256) void kStats2(const u16* __restrict__ y, float2* __restrict__ stats){
  __shared__ float ps[4], ps2[4];
  int bn = blockIdx.x, t = threadIdx.x;
  const u16* r = y + (size_t)bn*1536;
  float a0 = bf2f(r[t]), a1 = bf2f(r[t+256]), a2 = bf2f(r[t+512]);
  float s = a0+a1+a2, s2 = a0*a0 + a1*a1 + a2*a2;
  blockReduce2(s, s2, ps, ps2, t);
  float m   = s * (1.f/768.f);
  float var = s2 * (1.f/768.f) - m*m;
  if (t == 0) stats[bn] = make_float2(m, rsqrtf(var + 1e-3f));
}

// K3/K5: 64x64 tiled bf16 transpose [R rows x Cc cols] -> [Cc x R].
// If stats!=null, applies LN2 affine (fp32 math) to columns c<768 (u half).
__global__ __launch_bounds__(256) void kTrans(const u16* __restrict__ in, u16* __restrict__ out,
                                              int R, int Cc, const float2* __restrict__ stats,
                                              const float* __restrict__ g2, const float* __restrict__ be2){
  __shared__ float T[64][65];
  int ntc = Cc >> 6;
  int rt = blockIdx.x / ntc, ct = blockIdx.x % ntc;
  int r0 = rt << 6, c0 = ct << 6;
  int l = threadIdx.x & 63, q = threadIdx.x >> 6;
  bool doLN = (stats != nullptr) && (c0 < 768);
  float gv = 1.f, bv = 0.f;
  if (doLN){ gv = g2[c0 + l]; bv = be2[c0 + l]; }
  #pragma unroll
  for (int i = 0; i < 16; ++i){
    int r = (i << 2) + q;
    float val = bf2f(in[(size_t)(r0 + r)*Cc + c0 + l]);
    if (doLN){ float2 st = stats[r0 + r]; val = (val - st.x)*st.y*gv + bv; }
    T[l][r] = val;
  }
  __syncthreads();
  #pragma unroll
  for (int i = 0; i < 16; ++i){
    int c = (i << 2) + q;
    out[(size_t)(c0 + c)*R + r0 + l] = f2bf(T[c][l]);
  }
}

// K4 (MFMA): per-d GEMM [32(b) x 196(m)] @ W2[d][196 x 196] + b2^T, times v -> zT bf16.
// grid=768, block=256 (4 waves). A: u^T[d] bf16 swizzled LDS, K padded 196->224 (zeros).
// B: direct global->register fragments, predicated (k<196, n<196).
__global__ __launch_bounds__(256) void kSGU(const u16* __restrict__ yT, const float* __restrict__ W2,
                                            const float* __restrict__ b2, u16* __restrict__ zT){
  __shared__ unsigned char smA[16384];     // [32 b][256 m] bf16, 512 B pitch, swizzled
  int d = blockIdx.x, tid = threadIdx.x;
  const u16* up = yT + (size_t)d*6272;     // u^T[d]: [32 b][196 m] bf16

  // ---- stage A (predicated m<196, zero-padded to 256); rows only 8B-aligned ----
  {
    int r = tid >> 3;                                  // b row 0..31
    const unsigned char* srcb = (const unsigned char*)(up + r*196);
    #pragma unroll
    for (int i = 0; i < 4; ++i){
      int g = (tid & 7) + 8*i;                         // 16B group (8 bf16)
      int k0 = g*8;
      uint4 wv;
      if (k0 + 8 <= 196){
        uint2 lo = *(const uint2*)(srcb + k0*2);
        uint2 hi = *(const uint2*)(srcb + k0*2 + 8);
        wv = make_uint4(lo.x, lo.y, hi.x, hi.y);
      } else {
        const u16* s16 = (const u16*)srcb;
        u16 tmp[8];
        #pragma unroll
        for (int j = 0; j < 8; ++j){
          int k = k0 + j;
          tmp[j] = (k < 196) ? s16[k] : (u16)0;
        }
        wv.x = (u32)tmp[0] | ((u32)tmp[1] << 16);
        wv.y = (u32)tmp[2] | ((u32)tmp[3] << 16);
        wv.z = (u32)tmp[4] | ((u32)tmp[5] << 16);
        wv.w = (u32)tmp[6] | ((u32)tmp[7] << 16);
      }
      int byte = r*512 + ((g*16) ^ ((r & 7) << 4));
      *(uint4*)(smA + byte) = wv;
    }
  }

  int w = tid >> 6, l = tid & 63;
  int kb = (l >> 4) * 8;                               // k-subblock within k-step

  f32x4 acc[2][4];
  #pragma unroll
  for (int mt = 0; mt < 2; ++mt)
    #pragma unroll
    for (int t = 0; t < 4; ++t)
      acc[mt][t] = (f32x4){0.f, 0.f, 0.f, 0.f};

  // per-tile column info
  int  ncol[4]; bool nok[4];
  const float* wbs[4];
  #pragma unroll
  for (int t = 0; t < 4; ++t){
    int ntg = w + 4*t;
    int n = ntg*16 + (l & 15);
    ncol[t] = n;
    nok[t] = (ntg < 13) && (n < 196);
    wbs[t] = W2 + (size_t)d*38416 + (n < 196 ? n : 195);
  }

  __syncthreads();

  for (int ks = 0; ks < 7; ++ks){
    bf16x8 afr[2];
    #pragma unroll
    for (int mt = 0; mt < 2; ++mt){
      int row = mt*16 + (l & 15);
      int kbyte = ks*64 + ((l >> 4) << 4);
      afr[mt] = *(const bf16x8*)(smA + row*512 + (kbyte ^ ((row & 7) << 4)));
    }
    #pragma unroll
    for (int t = 0; t < 4; ++t){
      if (w + 4*t >= 13) continue;                     // wave-uniform skip
      bf16x8 bfr;
      #pragma unroll
      for (int j = 0; j < 8; ++j){
        int k = ks*32 + kb + j;
        float wv = wbs[t][(size_t)(k < 196 ? k : 195)*196];
        bfr[j] = bfbits((nok[t] && k < 196) ? wv : 0.f);
      }
      acc[0][t] = __builtin_amdgcn_mfma_f32_16x16x32_bf16(afr[0], bfr, acc[0][t], 0, 0, 0);
      acc[1][t] = __builtin_amdgcn_mfma_f32_16x16x32_bf16(afr[1], bfr, acc[1][t], 0, 0, 0);
    }
  }

  // ---- epilogue: +b2^T, *v, store zT[d][b*196+n] bf16 ----
  #pragma unroll
  for (int t = 0; t < 4; ++t){
    if (!nok[t]) continue;
    int n = ncol[t];
    float b2v = b2[(size_t)d*196 + n];
    const u16* vp = yT + (size_t)4816896 + (size_t)d*6272 + n;   // v half
    u16* zp = zT + (size_t)d*6272 + n;
    #pragma unroll
    for (int mt = 0; mt < 2; ++mt){
      #pragma unroll
      for (int r = 0; r < 4; ++r){
        int b = mt*16 + ((l >> 4) << 2) + r;
        float u2 = acc[mt][t][r] + b2v;
        zp[(size_t)b*196] = f2bf(u2 * bf2f(vp[(size_t)b*196]));
      }
    }
  }
}

// K6 (MFMA): per-(n, d-quarter) GEMM [32x192]@[192x256] -> fp32 partials.
// grid=196*4, block=256 (4 waves x 64 c-cols). A: swizzled bf16 LDS (copy only).
// B: direct global->register fragments.
__global__ __launch_bounds__(256) void kOut(const u16* __restrict__ z, const float* __restrict__ W3,
                                            float* __restrict__ part){
  __shared__ unsigned char smA[12288];     // [32 b][192 d] bf16, 384 B pitch, swizzled
  int bid = blockIdx.x;
  int n = bid >> 2, h = bid & 3;
  int tid = threadIdx.x;

  // ---- stage A: z[b][n*768 + h*192 .. +192] bf16 -> LDS ----
  {
    int r = tid >> 3;
    const unsigned char* src = (const unsigned char*)(z + ((size_t)(r*196 + n))*768 + h*192);
    #pragma unroll
    for (int i = 0; i < 3; ++i){
      int g = (tid & 7) + 8*i;                         // 16B-group 0..23
      uint4 wv = *(const uint4*)(src + g*16);
      int byte = r*384 + ((g*16) ^ ((r & 7) << 4));
      *(uint4*)(smA + byte) = wv;
    }
  }

  int w = tid >> 6, l = tid & 63;
  int col = w*64 + (l & 15);
  int kb  = (l >> 4) * 8;
  const float* wb = W3 + (size_t)n*196608 + (size_t)(h*192 + kb)*256 + col;

  f32x4 acc[2][4];
  #pragma unroll
  for (int mt = 0; mt < 2; ++mt)
    #pragma unroll
    for (int nt = 0; nt < 4; ++nt)
      acc[mt][nt] = (f32x4){0.f, 0.f, 0.f, 0.f};

  float cur[4][8], nxt[4][8];
  #pragma unroll
  for (int nt = 0; nt < 4; ++nt)
    #pragma unroll
    for (int j = 0; j < 8; ++j)
      cur[nt][j] = wb[(size_t)j*256 + nt*16];

  __syncthreads();

  #pragma unroll
  for (int ks = 0; ks < 6; ++ks){
    if (ks < 5){
      const float* wn = wb + (size_t)(ks+1)*32*256;
      #pragma unroll
      for (int nt = 0; nt < 4; ++nt)
        #pragma unroll
        for (int j = 0; j < 8; ++j)
          nxt[nt][j] = wn[(size_t)j*256 + nt*16];
    }
    bf16x8 bfr[4];
    #pragma unroll
    for (int nt = 0; nt < 4; ++nt)
      #pragma unroll
      for (int j = 0; j < 8; ++j)
        bfr[nt][j] = bfbits(cur[nt][j]);
    bf16x8 afr[2];
    #pragma unroll
    for (int mt = 0; mt < 2; ++mt){
      int row = mt*16 + (l & 15);
      int kbyte = ks*64 + ((l >> 4) << 4);
      afr[mt] = *(const bf16x8*)(smA + row*384 + (kbyte ^ ((row & 7) << 4)));
    }
    #pragma unroll
    for (int mt = 0; mt < 2; ++mt)
      #pragma unroll
      for (int nt = 0; nt < 4; ++nt)
        acc[mt][nt] = __builtin_amdgcn_mfma_f32_16x16x32_bf16(afr[mt], bfr[nt], acc[mt][nt], 0, 0, 0);
    if (ks < 5){
      #pragma unroll
      for (int nt = 0; nt < 4; ++nt)
        #pragma unroll
        for (int j = 0; j < 8; ++j)
          cur[nt][j] = nxt[nt][j];
    }
  }

  // ---- epilogue: write fp32 partials (layout: part[h][b][n][c]) ----
  #pragma unroll
  for (int nt = 0; nt < 4; ++nt){
    int c = w*64 + nt*16 + (l & 15);
    #pragma unroll
    for (int mt = 0; mt < 2; ++mt){
      #pragma unroll
      for (int r = 0; r < 4; ++r){
        int b = mt*16 + ((l >> 4) << 2) + r;
        part[(size_t)h*1605632 + (size_t)b*50176 + (size_t)n*256 + c] = acc[mt][nt][r];
      }
    }
  }
}

// K7: out = sum of 4 partials + b3 + x. grid=3136, block=256 (2 elems/thread)
__global__ __launch_bounds__(256) void kFinal(const float* __restrict__ part, const float* __restrict__ x,
                                              const float* __restrict__ b3, float* __restrict__ out){
  int i2 = blockIdx.x*256 + threadIdx.x;     // pair index < 802816
  size_t idx = (size_t)i2 * 2;
  const float2* p = (const float2*)part;
  float2 s0 = p[i2];
  float2 s1 = p[i2 + 802816];
  float2 s2 = p[i2 + 2*802816];
  float2 s3 = p[i2 + 3*802816];
  float lo = s0.x + s1.x + s2.x + s3.x;
  float hi = s0.y + s1.y + s2.y + s3.y;
  float2 xv = ((const float2*)x)[i2];
  unsigned int r = (unsigned int)(idx % 50176);   // b3 repeats per batch; r is even
  float2 bv = *(const float2*)(b3 + r);
  lo += xv.x + bv.x;
  hi += xv.y + bv.y;
  ((float2*)out)[i2] = make_float2(lo, hi);
}

extern "C" void kernel_launch(void* const* d_in, const int* in_sizes, int n_in,
                              void* d_out, int out_size, void* d_ws, size_t ws_size,
                              hipStream_t stream){
  const float* x   = (const float*)d_in[0];
  const float* g1  = (const float*)d_in[1];
  const float* be1 = (const float*)d_in[2];
  const float* W1  = (const float*)d_in[3];
  const float* b1  = (const float*)d_in[4];
  const float* g2  = (const float*)d_in[5];
  const float* be2 = (const float*)d_in[6];
  const float* W2  = (const float*)d_in[7];
  const float* b2  = (const float*)d_in[8];
  const float* W3  = (const float*)d_in[9];
  const float* b3  = (const float*)d_in[10];
  float* out = (float*)d_out;

  char* ws = (char*)d_ws;
  size_t off = 0;
  auto alloc = [&](size_t bytes) -> void* {
    void* p = ws + off;
    off += (bytes + 255) & ~(size_t)255;
    return p;
  };
  u16*    xn    = (u16*)   alloc((size_t)1605632*2);   // LN1 out, bf16
  u16*    y     = (u16*)   alloc((size_t)9633792*2);   // [6272][1536] bf16; reused for zT+z
  float2* stats = (float2*)alloc((size_t)6272*8);      // LN2 mean/rstd
  u16*    yT    = (u16*)   alloc((size_t)9633792*2);   // [1536][6272] bf16
  float*  part  = (float*) alloc((size_t)4*1605632*4); // fp32 partials
  if (off > ws_size) return;  // workspace too small; fail loudly in validation

  u16* zT = y;                 // [768][6272] bf16 (y dead by kSGU)
  u16* z  = y + 4816896;       // [6272][768] bf16

  kLN1   <<<6272, 256, 0, stream>>>(x, g1, be1, xn);
  kExpand<<<1176, 256, 0, stream>>>(xn, W1, b1, y);
  kStats2<<<6272, 256, 0, stream>>>(y, stats);
  kTrans <<<2352, 256, 0, stream>>>(y, yT, 6272, 1536, stats, g2, be2);
  kSGU   <<<768,  256, 0, stream>>>(yT, W2, b2, zT);
  kTrans <<<1176, 256, 0, stream>>>(zT, z, 768, 6272, nullptr, nullptr, nullptr);
  kOut   <<<784,  256, 0, stream>>>(z, W3, part);
  kFinal <<<3136, 256, 0, stream>>>(part, x, b3, out);
}